// Round 1
// baseline (1310.828 us; speedup 1.0000x reference)
//
#include <hip/hip_runtime.h>
#include <hip/hip_bf16.h>

// GAT (3-layer, HEADS=4, HID=32, concat=False head-mean) + global mean pool + MLP.
// Strategy: build CSR-by-dst once (histogram -> scan -> scatter), then per layer:
//   gemm_h: h = x@W            [N,FIN] -> [N,128]   (f32 vector, x-tile in LDS)
//   alphas: asrc/adst = einsum(h, a_s/a_d)          (per-node 128-thread reduce)
//   aggregate: per-dst softmax over edges + weighted gather of h[src], head-mean,
//              +bias, relu  (one 128-thread block per node, no atomics)
// Finally: global mean pool (block partials + 32 atomicAdds) + tiny MLP.

#define HEADS 4
#define HID 32
#define F_HID 128   // HEADS*HID
#define NEG_SLOPE 0.2f

__device__ __forceinline__ float lrelu(float v) { return v > 0.f ? v : NEG_SLOPE * v; }

// ---------------- CSR build ----------------

__global__ void deg_hist(const int* __restrict__ ei, int E, int* __restrict__ deg) {
    int i = blockIdx.x * blockDim.x + threadIdx.x;
    if (i < E) {
        int d = ei[E + i];          // dst row of edge_index
        atomicAdd(&deg[d], 1);
    }
}

__global__ void scan_partial(const int* __restrict__ deg, int n, int* __restrict__ partial) {
    __shared__ int sm[256];
    int t = threadIdx.x;
    int i = blockIdx.x * 256 + t;
    sm[t] = (i < n) ? deg[i] : 0;
    __syncthreads();
    for (int s = 128; s > 0; s >>= 1) {
        if (t < s) sm[t] += sm[t + s];
        __syncthreads();
    }
    if (t == 0) partial[blockIdx.x] = sm[0];
}

__global__ void scan_exclusive(int* partial, int B) {
    // single thread: B ~ 391, trivial
    int run = 0;
    for (int b = 0; b < B; b++) { int v = partial[b]; partial[b] = run; run += v; }
}

__global__ void scan_final(const int* __restrict__ deg, int n, const int* __restrict__ partial,
                           int* __restrict__ row_start, int* __restrict__ cursor) {
    __shared__ int sm[256];
    int t = threadIdx.x;
    int i = blockIdx.x * 256 + t;
    int v = (i < n) ? deg[i] : 0;
    sm[t] = v;
    __syncthreads();
    for (int s = 1; s < 256; s <<= 1) {
        int add = (t >= s) ? sm[t - s] : 0;
        __syncthreads();
        sm[t] += add;
        __syncthreads();
    }
    if (i < n) {
        int excl = partial[blockIdx.x] + sm[t] - v;
        row_start[i] = excl;
        cursor[i] = excl;
    }
}

__global__ void scatter_edges(const int* __restrict__ ei, int E,
                              int* __restrict__ cursor, int* __restrict__ csr_src) {
    int i = blockIdx.x * blockDim.x + threadIdx.x;
    if (i < E) {
        int s = ei[i];
        int d = ei[E + i];
        int pos = atomicAdd(&cursor[d], 1);
        csr_src[pos] = s;
    }
}

// ---------------- per-layer kernels ----------------

// h = x @ W  ([N,FIN] @ [FIN,128]). 32 nodes per 256-thread block; x-tile in LDS,
// W read via L1/L2 (amortized). Thread = 2 cols x 8 nodes.
template <int FIN>
__global__ __launch_bounds__(256) void gemm_h(const float* __restrict__ x,
                                              const float* __restrict__ W,
                                              float* __restrict__ h, int n) {
    constexpr int NPB = 32;
    __shared__ float xs[NPB * FIN];
    int t = threadIdx.x;
    int base = blockIdx.x * NPB;
    int nn = n - base; if (nn > NPB) nn = NPB;
    for (int i = t; i < nn * FIN; i += 256) xs[i] = x[(size_t)base * FIN + i];
    for (int i = nn * FIN + t; i < NPB * FIN; i += 256) xs[i] = 0.f;
    __syncthreads();

    int grp = t >> 6;       // 0..3, each grp = one wave, 8 nodes
    int l = t & 63;
    int col0 = l * 2;

    float acc[8][2];
#pragma unroll
    for (int j = 0; j < 8; j++) { acc[j][0] = 0.f; acc[j][1] = 0.f; }

#pragma unroll 4
    for (int k = 0; k < FIN; k++) {
        float2 wv = *(const float2*)&W[k * F_HID + col0];
#pragma unroll
        for (int j = 0; j < 8; j++) {
            float xv = xs[(grp * 8 + j) * FIN + k];
            acc[j][0] += xv * wv.x;
            acc[j][1] += xv * wv.y;
        }
    }
#pragma unroll
    for (int j = 0; j < 8; j++) {
        int node = base + grp * 8 + j;
        if (node < n) {
            h[(size_t)node * F_HID + col0] = acc[j][0];
            h[(size_t)node * F_HID + col0 + 1] = acc[j][1];
        }
    }
}

// asrc[n,hd] = sum_c h[n,hd,c]*a_s[hd,c]; same for adst. One node per 128-thread block.
__global__ __launch_bounds__(128) void alphas(const float* __restrict__ h,
                                              const float* __restrict__ a_s,
                                              const float* __restrict__ a_d,
                                              float* __restrict__ asrc,
                                              float* __restrict__ adst, int n) {
    int node = blockIdx.x;
    int t = threadIdx.x;          // t = hd*32 + c
    float v = h[(size_t)node * F_HID + t];
    float vs = v * a_s[t];
    float vd = v * a_d[t];
#pragma unroll
    for (int off = 16; off > 0; off >>= 1) {
        vs += __shfl_xor(vs, off);
        vd += __shfl_xor(vd, off);
    }
    if ((t & 31) == 0) {
        int hd = t >> 5;
        asrc[node * HEADS + hd] = vs;
        adst[node * HEADS + hd] = vd;
    }
}

// Per-dst softmax + weighted gather + head mean + bias + relu.
// Block = 128 threads (hd*32+c), one node per block. Self-loop handled implicitly.
__global__ __launch_bounds__(128) void aggregate(const float* __restrict__ h,
                                                 const float* __restrict__ asrc,
                                                 const float* __restrict__ adst,
                                                 const int* __restrict__ row_start,
                                                 const int* __restrict__ deg,
                                                 const int* __restrict__ csr_src,
                                                 const float* __restrict__ bias,
                                                 float* __restrict__ xout, int n) {
    int d = blockIdx.x;
    int t = threadIdx.x;
    int hd = t >> 5;
    int start = row_start[d];
    int cnt = deg[d];
    float ad = adst[d * HEADS + hd];

    // pass 1: max (incl. self-loop)
    float e_self = lrelu(asrc[d * HEADS + hd] + ad);
    float m = e_self;
    for (int j = 0; j < cnt; j++) {
        int s = csr_src[start + j];
        float e = lrelu(asrc[s * HEADS + hd] + ad);
        m = fmaxf(m, e);
    }

    // pass 2: exp-sum + weighted gather
    float p = expf(e_self - m);
    float denom = p;
    float acc = p * h[(size_t)d * F_HID + t];
    for (int j = 0; j < cnt; j++) {
        int s = csr_src[start + j];
        float e = lrelu(asrc[s * HEADS + hd] + ad);
        float pe = expf(e - m);
        denom += pe;
        acc += pe * h[(size_t)s * F_HID + t];
    }
    float r = acc / (denom + 1e-16f);

    __shared__ float sm[128];
    sm[t] = r;
    __syncthreads();
    if (t < HID) {
        float v = 0.25f * (sm[t] + sm[t + 32] + sm[t + 64] + sm[t + 96]) + bias[t];
        xout[(size_t)d * HID + t] = v > 0.f ? v : 0.f;
    }
}

// ---------------- pooling + MLP ----------------

__global__ void pool_sum(const float* __restrict__ x, int n, float* __restrict__ g) {
    __shared__ float sm[256];
    int t = threadIdx.x;
    int c = t & 31;
    int r = t >> 5;   // 8 node-rows per block
    float acc = 0.f;
    for (int i = blockIdx.x * 8 + r; i < n; i += gridDim.x * 8)
        acc += x[(size_t)i * HID + c];
    sm[t] = acc;
    __syncthreads();
    if (t < 32) {
        float v = 0.f;
#pragma unroll
        for (int k = 0; k < 8; k++) v += sm[t + 32 * k];
        atomicAdd(&g[t], v);
    }
}

__global__ void mlp_final(const float* __restrict__ g,
                          const float* __restrict__ lw1, const float* __restrict__ lb1,
                          const float* __restrict__ lw2, const float* __restrict__ lb2,
                          float* __restrict__ out, float invn) {
    if (threadIdx.x == 0 && blockIdx.x == 0) {
        float gm[32];
        for (int c = 0; c < 32; c++) gm[c] = g[c] * invn;
        float o = lb2[0];
        for (int j = 0; j < 16; j++) {
            float q = lb1[j];
            for (int c = 0; c < 32; c++) q += gm[c] * lw1[c * 16 + j];
            q = q > 0.f ? q : 0.f;
            o += q * lw2[j];
        }
        out[0] = o;
    }
}

// ---------------- launch ----------------

extern "C" void kernel_launch(void* const* d_in, const int* in_sizes, int n_in,
                              void* d_out, int out_size, void* d_ws, size_t ws_size,
                              hipStream_t stream) {
    const float* x   = (const float*)d_in[0];
    const int*   ei  = (const int*)d_in[1];
    const float* W1  = (const float*)d_in[2];
    const float* as1 = (const float*)d_in[3];
    const float* ad1 = (const float*)d_in[4];
    const float* b1  = (const float*)d_in[5];
    const float* W2  = (const float*)d_in[6];
    const float* as2 = (const float*)d_in[7];
    const float* ad2 = (const float*)d_in[8];
    const float* b2  = (const float*)d_in[9];
    const float* W3  = (const float*)d_in[10];
    const float* as3 = (const float*)d_in[11];
    const float* ad3 = (const float*)d_in[12];
    const float* b3  = (const float*)d_in[13];
    const float* lw1 = (const float*)d_in[14];
    const float* lb1 = (const float*)d_in[15];
    const float* lw2 = (const float*)d_in[16];
    const float* lb2 = (const float*)d_in[17];
    float* out = (float*)d_out;

    int n = in_sizes[0] / 128;   // 100000
    int E = in_sizes[1] / 2;     // 1600000
    int B = (n + 255) / 256;

    // workspace carve (256B aligned)
    char* p = (char*)d_ws;
    auto alloc = [&](size_t bytes) -> void* {
        void* r = (void*)p;
        p += (bytes + 255) & ~(size_t)255;
        return r;
    };
    int* deg       = (int*)alloc((size_t)n * 4);
    int* row_start = (int*)alloc((size_t)n * 4);
    int* cursor    = (int*)alloc((size_t)n * 4);
    int* partial   = (int*)alloc((size_t)B * 4);
    int* csr       = (int*)alloc((size_t)E * 4);
    float* asrc    = (float*)alloc((size_t)n * HEADS * 4);
    float* adst    = (float*)alloc((size_t)n * HEADS * 4);
    float* h       = (float*)alloc((size_t)n * F_HID * 4);
    float* xA      = (float*)alloc((size_t)n * HID * 4);
    float* xB      = (float*)alloc((size_t)n * HID * 4);
    float* g       = (float*)alloc(32 * 4);

    // CSR build (shared across all 3 layers)
    hipMemsetAsync(deg, 0, (size_t)n * 4, stream);
    deg_hist<<<(E + 255) / 256, 256, 0, stream>>>(ei, E, deg);
    scan_partial<<<B, 256, 0, stream>>>(deg, n, partial);
    scan_exclusive<<<1, 1, 0, stream>>>(partial, B);
    scan_final<<<B, 256, 0, stream>>>(deg, n, partial, row_start, cursor);
    scatter_edges<<<(E + 255) / 256, 256, 0, stream>>>(ei, E, cursor, csr);

    int gb = (n + 31) / 32;

    // layer 1
    gemm_h<128><<<gb, 256, 0, stream>>>(x, W1, h, n);
    alphas<<<n, 128, 0, stream>>>(h, as1, ad1, asrc, adst, n);
    aggregate<<<n, 128, 0, stream>>>(h, asrc, adst, row_start, deg, csr, b1, xA, n);

    // layer 2
    gemm_h<32><<<gb, 256, 0, stream>>>(xA, W2, h, n);
    alphas<<<n, 128, 0, stream>>>(h, as2, ad2, asrc, adst, n);
    aggregate<<<n, 128, 0, stream>>>(h, asrc, adst, row_start, deg, csr, b2, xB, n);

    // layer 3
    gemm_h<32><<<gb, 256, 0, stream>>>(xB, W3, h, n);
    alphas<<<n, 128, 0, stream>>>(h, as3, ad3, asrc, adst, n);
    aggregate<<<n, 128, 0, stream>>>(h, asrc, adst, row_start, deg, csr, b3, xA, n);

    // pooling + MLP
    hipMemsetAsync(g, 0, 32 * 4, stream);
    pool_sum<<<256, 256, 0, stream>>>(xA, n, g);
    mlp_final<<<1, 64, 0, stream>>>(g, lw1, lb1, lw2, lb2, out, 1.0f / (float)n);
}

// Round 2
// 905.419 us; speedup vs baseline: 1.4478x; 1.4478x over previous
//
#include <hip/hip_runtime.h>
#include <hip/hip_bf16.h>

// GAT (3-layer, HEADS=4, HID=32, concat=False head-mean) + global mean pool + MLP.
// R2: wave-per-node aggregate (lane-parallel edge alphas, shfl broadcast gather),
//     float4-LDS gemm, float4 alphas.

#define HEADS 4
#define HID 32
#define F_HID 128   // HEADS*HID
#define NEG_SLOPE 0.2f

__device__ __forceinline__ float lrelu(float v) { return v > 0.f ? v : NEG_SLOPE * v; }

// ---------------- CSR build ----------------

__global__ void deg_hist(const int* __restrict__ ei, int E, int* __restrict__ deg) {
    int i = blockIdx.x * blockDim.x + threadIdx.x;
    if (i < E) {
        int d = ei[E + i];          // dst row of edge_index
        atomicAdd(&deg[d], 1);
    }
}

__global__ void scan_partial(const int* __restrict__ deg, int n, int* __restrict__ partial) {
    __shared__ int sm[256];
    int t = threadIdx.x;
    int i = blockIdx.x * 256 + t;
    sm[t] = (i < n) ? deg[i] : 0;
    __syncthreads();
    for (int s = 128; s > 0; s >>= 1) {
        if (t < s) sm[t] += sm[t + s];
        __syncthreads();
    }
    if (t == 0) partial[blockIdx.x] = sm[0];
}

__global__ void scan_exclusive(int* partial, int B) {
    int run = 0;
    for (int b = 0; b < B; b++) { int v = partial[b]; partial[b] = run; run += v; }
}

__global__ void scan_final(const int* __restrict__ deg, int n, const int* __restrict__ partial,
                           int* __restrict__ row_start, int* __restrict__ cursor) {
    __shared__ int sm[256];
    int t = threadIdx.x;
    int i = blockIdx.x * 256 + t;
    int v = (i < n) ? deg[i] : 0;
    sm[t] = v;
    __syncthreads();
    for (int s = 1; s < 256; s <<= 1) {
        int add = (t >= s) ? sm[t - s] : 0;
        __syncthreads();
        sm[t] += add;
        __syncthreads();
    }
    if (i < n) {
        int excl = partial[blockIdx.x] + sm[t] - v;
        row_start[i] = excl;
        cursor[i] = excl;
    }
}

__global__ void scatter_edges(const int* __restrict__ ei, int E,
                              int* __restrict__ cursor, int* __restrict__ csr_src) {
    int i = blockIdx.x * blockDim.x + threadIdx.x;
    if (i < E) {
        int s = ei[i];
        int d = ei[E + i];
        int pos = atomicAdd(&cursor[d], 1);
        csr_src[pos] = s;
    }
}

// ---------------- per-layer kernels ----------------

// h = x @ W  ([N,FIN] @ [FIN,128]). 32 nodes per 256-thread block; x-tile in LDS
// read back as float4 (ds_read_b128, wave-uniform broadcast). Thread = 2 cols x 8 nodes.
template <int FIN>
__global__ __launch_bounds__(256) void gemm_h(const float* __restrict__ x,
                                              const float* __restrict__ W,
                                              float* __restrict__ h, int n) {
    constexpr int NPB = 32;
    __shared__ float xs[NPB * FIN];
    int t = threadIdx.x;
    int base = blockIdx.x * NPB;
    int nn = n - base; if (nn > NPB) nn = NPB;

    {   // stage x tile (float4)
        const float4* xg = (const float4*)(x + (size_t)base * FIN);
        float4* xs4 = (float4*)xs;
        int tot4 = nn * FIN / 4;
        for (int i = t; i < tot4; i += 256) xs4[i] = xg[i];
        for (int i = tot4 * 4 + t; i < NPB * FIN; i += 256) xs[i] = 0.f;
    }
    __syncthreads();

    int grp = t >> 6;       // 0..3, each grp = one wave, 8 nodes
    int l = t & 63;
    int col0 = l * 2;

    float2 acc[8];
#pragma unroll
    for (int j = 0; j < 8; j++) { acc[j].x = 0.f; acc[j].y = 0.f; }

    for (int k4 = 0; k4 < FIN; k4 += 4) {
        float4 xv[8];
#pragma unroll
        for (int j = 0; j < 8; j++)
            xv[j] = *(const float4*)&xs[(grp * 8 + j) * FIN + k4];
#pragma unroll
        for (int kk = 0; kk < 4; kk++) {
            float2 wv = *(const float2*)&W[(size_t)(k4 + kk) * F_HID + col0];
#pragma unroll
            for (int j = 0; j < 8; j++) {
                float xk = (&xv[j].x)[kk];
                acc[j].x += xk * wv.x;
                acc[j].y += xk * wv.y;
            }
        }
    }
#pragma unroll
    for (int j = 0; j < 8; j++) {
        int node = base + grp * 8 + j;
        if (node < n)
            *(float2*)&h[(size_t)node * F_HID + col0] = acc[j];
    }
}

// asrc[n,hd] = sum_c h[n,hd,c]*a_s[hd,c]; same for adst. 8 nodes per 256-thread block.
__global__ __launch_bounds__(256) void alphas(const float4* __restrict__ h4,
                                              const float4* __restrict__ as4,
                                              const float4* __restrict__ ad4,
                                              float* __restrict__ asrc,
                                              float* __restrict__ adst, int n) {
    int t = threadIdx.x;
    int node = blockIdx.x * 8 + (t >> 5);
    if (node >= n) return;
    int li = t & 31;                 // li covers channels 4li..4li+3; head = li>>3
    float4 v = h4[(size_t)node * 32 + li];
    float4 ws = as4[li];
    float4 wd = ad4[li];
    float vs = v.x * ws.x + v.y * ws.y + v.z * ws.z + v.w * ws.w;
    float vd = v.x * wd.x + v.y * wd.y + v.z * wd.z + v.w * wd.w;
#pragma unroll
    for (int off = 4; off >= 1; off >>= 1) {
        vs += __shfl_xor(vs, off);
        vd += __shfl_xor(vd, off);
    }
    if ((li & 7) == 0) {
        int hd = li >> 3;
        asrc[node * HEADS + hd] = vs;
        adst[node * HEADS + hd] = vd;
    }
}

// Wave-per-node softmax + weighted gather + head mean + bias + relu.
// lane l: hd = l>>4 (head), ci = l&15 (channel pair 2ci,2ci+1 within head).
__global__ __launch_bounds__(256) void aggregate(const float2* __restrict__ h2,
                                                 const float* __restrict__ asrc,
                                                 const float* __restrict__ adst,
                                                 const int* __restrict__ row_start,
                                                 const int* __restrict__ deg,
                                                 const int* __restrict__ csr_src,
                                                 const float* __restrict__ bias,
                                                 float* __restrict__ xout, int n) {
    int d = blockIdx.x * 4 + (threadIdx.x >> 6);
    if (d >= n) return;
    int l = threadIdx.x & 63;
    int hd = l >> 4;
    int ci = l & 15;
    int start = row_start[d];
    int cnt = deg[d];
    float ad = adst[d * HEADS + hd];
    float e_self = lrelu(asrc[d * HEADS + hd] + ad);

    // pass 1: per-head max over edges (lane-parallel, 16 edges/chunk)
    float m = e_self;
    for (int j0 = 0; j0 < cnt; j0 += 16) {
        int j = j0 + ci;
        float e = -1e30f;
        if (j < cnt) {
            int s = csr_src[start + j];
            e = lrelu(asrc[s * HEADS + hd] + ad);
        }
#pragma unroll
        for (int off = 8; off >= 1; off >>= 1) e = fmaxf(e, __shfl_xor(e, off));
        m = fmaxf(m, e);
    }
    // m uniform within each 16-lane head group

    float p_self = __expf(e_self - m);
    float dsum = 0.f;
    float2 hv = h2[(size_t)d * 64 + hd * 16 + ci];
    float ax = p_self * hv.x, ay = p_self * hv.y;

    // pass 2: exp + weighted gather (pe computed once/head, broadcast via shfl)
    for (int j0 = 0; j0 < cnt; j0 += 16) {
        int j = j0 + ci;
        int s = 0;
        float pe = 0.f;
        if (j < cnt) {
            s = csr_src[start + j];
            pe = __expf(lrelu(asrc[s * HEADS + hd] + ad) - m);
        }
        dsum += pe;
        int vcnt = cnt - j0; if (vcnt > 16) vcnt = 16;
        for (int jj = 0; jj < vcnt; jj++) {
            float pej = __shfl(pe, jj, 16);
            int sj = __builtin_amdgcn_readlane(s, jj);   // src uniform across heads
            float2 hj = h2[(size_t)sj * 64 + hd * 16 + ci];
            ax += pej * hj.x;
            ay += pej * hj.y;
        }
    }
#pragma unroll
    for (int off = 8; off >= 1; off >>= 1) dsum += __shfl_xor(dsum, off);
    float inv = 1.f / (p_self + dsum + 1e-16f);
    ax *= inv; ay *= inv;

    // head mean: lanes l, l^16, l^32, l^48 hold same channel pair across heads
    ax += __shfl_xor(ax, 16); ax += __shfl_xor(ax, 32);
    ay += __shfl_xor(ay, 16); ay += __shfl_xor(ay, 32);
    if (hd == 0) {
        float2 bv = *(const float2*)&bias[2 * ci];
        float ox = 0.25f * ax + bv.x;
        float oy = 0.25f * ay + bv.y;
        float2 o;
        o.x = ox > 0.f ? ox : 0.f;
        o.y = oy > 0.f ? oy : 0.f;
        *(float2*)&xout[(size_t)d * HID + 2 * ci] = o;
    }
}

// ---------------- pooling + MLP ----------------

__global__ void pool_sum(const float* __restrict__ x, int n, float* __restrict__ g) {
    __shared__ float sm[256];
    int t = threadIdx.x;
    int c = t & 31;
    int r = t >> 5;   // 8 node-rows per block
    float acc = 0.f;
    for (int i = blockIdx.x * 8 + r; i < n; i += gridDim.x * 8)
        acc += x[(size_t)i * HID + c];
    sm[t] = acc;
    __syncthreads();
    if (t < 32) {
        float v = 0.f;
#pragma unroll
        for (int k = 0; k < 8; k++) v += sm[t + 32 * k];
        atomicAdd(&g[t], v);
    }
}

__global__ void mlp_final(const float* __restrict__ g,
                          const float* __restrict__ lw1, const float* __restrict__ lb1,
                          const float* __restrict__ lw2, const float* __restrict__ lb2,
                          float* __restrict__ out, float invn) {
    if (threadIdx.x == 0 && blockIdx.x == 0) {
        float gm[32];
        for (int c = 0; c < 32; c++) gm[c] = g[c] * invn;
        float o = lb2[0];
        for (int j = 0; j < 16; j++) {
            float q = lb1[j];
            for (int c = 0; c < 32; c++) q += gm[c] * lw1[c * 16 + j];
            q = q > 0.f ? q : 0.f;
            o += q * lw2[j];
        }
        out[0] = o;
    }
}

// ---------------- launch ----------------

extern "C" void kernel_launch(void* const* d_in, const int* in_sizes, int n_in,
                              void* d_out, int out_size, void* d_ws, size_t ws_size,
                              hipStream_t stream) {
    const float* x   = (const float*)d_in[0];
    const int*   ei  = (const int*)d_in[1];
    const float* W1  = (const float*)d_in[2];
    const float* as1 = (const float*)d_in[3];
    const float* ad1 = (const float*)d_in[4];
    const float* b1  = (const float*)d_in[5];
    const float* W2  = (const float*)d_in[6];
    const float* as2 = (const float*)d_in[7];
    const float* ad2 = (const float*)d_in[8];
    const float* b2  = (const float*)d_in[9];
    const float* W3  = (const float*)d_in[10];
    const float* as3 = (const float*)d_in[11];
    const float* ad3 = (const float*)d_in[12];
    const float* b3  = (const float*)d_in[13];
    const float* lw1 = (const float*)d_in[14];
    const float* lb1 = (const float*)d_in[15];
    const float* lw2 = (const float*)d_in[16];
    const float* lb2 = (const float*)d_in[17];
    float* out = (float*)d_out;

    int n = in_sizes[0] / 128;   // 100000
    int E = in_sizes[1] / 2;     // 1600000
    int B = (n + 255) / 256;

    // workspace carve (256B aligned)
    char* p = (char*)d_ws;
    auto alloc = [&](size_t bytes) -> void* {
        void* r = (void*)p;
        p += (bytes + 255) & ~(size_t)255;
        return r;
    };
    int* deg       = (int*)alloc((size_t)n * 4);
    int* row_start = (int*)alloc((size_t)n * 4);
    int* cursor    = (int*)alloc((size_t)n * 4);
    int* partial   = (int*)alloc((size_t)B * 4);
    int* csr       = (int*)alloc((size_t)E * 4);
    float* asrc    = (float*)alloc((size_t)n * HEADS * 4);
    float* adst    = (float*)alloc((size_t)n * HEADS * 4);
    float* h       = (float*)alloc((size_t)n * F_HID * 4);
    float* xA      = (float*)alloc((size_t)n * HID * 4);
    float* xB      = (float*)alloc((size_t)n * HID * 4);
    float* g       = (float*)alloc(32 * 4);

    // CSR build (shared across all 3 layers)
    hipMemsetAsync(deg, 0, (size_t)n * 4, stream);
    deg_hist<<<(E + 255) / 256, 256, 0, stream>>>(ei, E, deg);
    scan_partial<<<B, 256, 0, stream>>>(deg, n, partial);
    scan_exclusive<<<1, 1, 0, stream>>>(partial, B);
    scan_final<<<B, 256, 0, stream>>>(deg, n, partial, row_start, cursor);
    scatter_edges<<<(E + 255) / 256, 256, 0, stream>>>(ei, E, cursor, csr);

    int gb = (n + 31) / 32;
    int ab = (n + 7) / 8;
    int ggb = (n + 3) / 4;

    // layer 1
    gemm_h<128><<<gb, 256, 0, stream>>>(x, W1, h, n);
    alphas<<<ab, 256, 0, stream>>>((const float4*)h, (const float4*)as1, (const float4*)ad1, asrc, adst, n);
    aggregate<<<ggb, 256, 0, stream>>>((const float2*)h, asrc, adst, row_start, deg, csr, b1, xA, n);

    // layer 2
    gemm_h<32><<<gb, 256, 0, stream>>>(xA, W2, h, n);
    alphas<<<ab, 256, 0, stream>>>((const float4*)h, (const float4*)as2, (const float4*)ad2, asrc, adst, n);
    aggregate<<<ggb, 256, 0, stream>>>((const float2*)h, asrc, adst, row_start, deg, csr, b2, xB, n);

    // layer 3
    gemm_h<32><<<gb, 256, 0, stream>>>(xB, W3, h, n);
    alphas<<<ab, 256, 0, stream>>>((const float4*)h, (const float4*)as3, (const float4*)ad3, asrc, adst, n);
    aggregate<<<ggb, 256, 0, stream>>>((const float2*)h, asrc, adst, row_start, deg, csr, b3, xA, n);

    // pooling + MLP
    hipMemsetAsync(g, 0, 32 * 4, stream);
    pool_sum<<<256, 256, 0, stream>>>(xA, n, g);
    mlp_final<<<1, 64, 0, stream>>>(g, lw1, lb1, lw2, lb2, out, 1.0f / (float)n);
}

// Round 3
// 830.537 us; speedup vs baseline: 1.5783x; 1.0902x over previous
//
#include <hip/hip_runtime.h>
#include <hip/hip_bf16.h>

// GAT (3-layer, HEADS=4, HID=32, concat=False head-mean) + global mean pool + MLP.
// R3: single-pass online-softmax aggregate with fully-unrolled 16-deep gather
//     (16 loads in flight/wave), alphas fused into gemm epilogue, parallel scan,
//     parallel final MLP.

#define HEADS 4
#define HID 32
#define F_HID 128   // HEADS*HID
#define NEG_SLOPE 0.2f

__device__ __forceinline__ float lrelu(float v) { return v > 0.f ? v : NEG_SLOPE * v; }

// ---------------- CSR build ----------------

__global__ void deg_hist(const int* __restrict__ ei, int E, int* __restrict__ deg) {
    int i = blockIdx.x * blockDim.x + threadIdx.x;
    if (i < E) {
        int d = ei[E + i];          // dst row of edge_index
        atomicAdd(&deg[d], 1);
    }
}

__global__ void scan_partial(const int* __restrict__ deg, int n, int* __restrict__ partial) {
    __shared__ int sm[256];
    int t = threadIdx.x;
    int i = blockIdx.x * 256 + t;
    sm[t] = (i < n) ? deg[i] : 0;
    __syncthreads();
    for (int s = 128; s > 0; s >>= 1) {
        if (t < s) sm[t] += sm[t + s];
        __syncthreads();
    }
    if (t == 0) partial[blockIdx.x] = sm[0];
}

// single-block parallel exclusive scan over B partials (B can exceed 512 via chunks)
__global__ __launch_bounds__(512) void scan_exclusive(int* partial, int B) {
    __shared__ int sm[512];
    int t = threadIdx.x;
    int carry = 0;
    for (int base = 0; base < B; base += 512) {
        int v = (base + t < B) ? partial[base + t] : 0;
        sm[t] = v;
        __syncthreads();
        for (int s = 1; s < 512; s <<= 1) {
            int add = (t >= s) ? sm[t - s] : 0;
            __syncthreads();
            sm[t] += add;
            __syncthreads();
        }
        if (base + t < B) partial[base + t] = carry + sm[t] - v;
        carry += sm[511];
        __syncthreads();
    }
}

__global__ void scan_final(const int* __restrict__ deg, int n, const int* __restrict__ partial,
                           int* __restrict__ row_start, int* __restrict__ cursor) {
    __shared__ int sm[256];
    int t = threadIdx.x;
    int i = blockIdx.x * 256 + t;
    int v = (i < n) ? deg[i] : 0;
    sm[t] = v;
    __syncthreads();
    for (int s = 1; s < 256; s <<= 1) {
        int add = (t >= s) ? sm[t - s] : 0;
        __syncthreads();
        sm[t] += add;
        __syncthreads();
    }
    if (i < n) {
        int excl = partial[blockIdx.x] + sm[t] - v;
        row_start[i] = excl;
        cursor[i] = excl;
    }
}

__global__ void scatter_edges(const int* __restrict__ ei, int E,
                              int* __restrict__ cursor, int* __restrict__ csr_src) {
    int i = blockIdx.x * blockDim.x + threadIdx.x;
    if (i < E) {
        int s = ei[i];
        int d = ei[E + i];
        int pos = atomicAdd(&cursor[d], 1);
        csr_src[pos] = s;
    }
}

// ---------------- per-layer kernels ----------------

// h = x @ W ([N,FIN] @ [FIN,128]) with fused alpha epilogue.
// 32 nodes per 256-thread block; x-tile in LDS (float4 reads). Thread = 2 cols x 8 nodes.
template <int FIN>
__global__ __launch_bounds__(256) void gemm_h(const float* __restrict__ x,
                                              const float* __restrict__ W,
                                              const float* __restrict__ a_s,
                                              const float* __restrict__ a_d,
                                              float* __restrict__ h,
                                              float* __restrict__ asrc,
                                              float* __restrict__ adst, int n) {
    constexpr int NPB = 32;
    __shared__ float xs[NPB * FIN];
    int t = threadIdx.x;
    int base = blockIdx.x * NPB;
    int nn = n - base; if (nn > NPB) nn = NPB;

    {   // stage x tile (float4)
        const float4* xg = (const float4*)(x + (size_t)base * FIN);
        float4* xs4 = (float4*)xs;
        int tot4 = nn * FIN / 4;
        for (int i = t; i < tot4; i += 256) xs4[i] = xg[i];
        for (int i = tot4 * 4 + t; i < NPB * FIN; i += 256) xs[i] = 0.f;
    }
    __syncthreads();

    int grp = t >> 6;       // 0..3, each grp = one wave, 8 nodes
    int l = t & 63;
    int col0 = l * 2;

    float2 acc[8];
#pragma unroll
    for (int j = 0; j < 8; j++) { acc[j].x = 0.f; acc[j].y = 0.f; }

    for (int k4 = 0; k4 < FIN; k4 += 4) {
        float4 xv[8];
#pragma unroll
        for (int j = 0; j < 8; j++)
            xv[j] = *(const float4*)&xs[(grp * 8 + j) * FIN + k4];
#pragma unroll
        for (int kk = 0; kk < 4; kk++) {
            float2 wv = *(const float2*)&W[(size_t)(k4 + kk) * F_HID + col0];
#pragma unroll
            for (int j = 0; j < 8; j++) {
                float xk = (&xv[j].x)[kk];
                acc[j].x += xk * wv.x;
                acc[j].y += xk * wv.y;
            }
        }
    }

    float ws0 = a_s[col0], ws1 = a_s[col0 + 1];
    float wd0 = a_d[col0], wd1 = a_d[col0 + 1];
#pragma unroll
    for (int j = 0; j < 8; j++) {
        int node = base + grp * 8 + j;
        bool ok = node < n;
        if (ok) *(float2*)&h[(size_t)node * F_HID + col0] = acc[j];
        float vs = acc[j].x * ws0 + acc[j].y * ws1;
        float vd = acc[j].x * wd0 + acc[j].y * wd1;
#pragma unroll
        for (int off = 8; off >= 1; off >>= 1) {
            vs += __shfl_xor(vs, off);
            vd += __shfl_xor(vd, off);
        }
        if (ok && (l & 15) == 0) {
            int hd = l >> 4;
            asrc[node * HEADS + hd] = vs;
            adst[node * HEADS + hd] = vd;
        }
    }
}

// Wave-per-node single-pass online-softmax aggregate.
// lane l: hd = l>>4 (head), ci = l&15 (channel pair 2ci,2ci+1 within head).
// Gather loop fully unrolled 16-deep: 16 independent loads in flight per wave.
__global__ __launch_bounds__(256) void aggregate(const float2* __restrict__ h2,
                                                 const float* __restrict__ asrc,
                                                 const float* __restrict__ adst,
                                                 const int* __restrict__ row_start,
                                                 const int* __restrict__ deg,
                                                 const int* __restrict__ csr_src,
                                                 const float* __restrict__ bias,
                                                 float* __restrict__ xout, int n) {
    int d = blockIdx.x * 4 + (threadIdx.x >> 6);
    if (d >= n) return;
    int l = threadIdx.x & 63;
    int hd = l >> 4;
    int ci = l & 15;
    int start = row_start[d];
    int cnt = deg[d];
    float ad = adst[d * HEADS + hd];
    float e_self = lrelu(asrc[d * HEADS + hd] + ad);

    float m = e_self;
    float dsum = 0.f;
    float ax = 0.f, ay = 0.f;

    for (int j0 = 0; j0 < cnt; j0 += 16) {
        int ncnt = cnt - j0; if (ncnt > 16) ncnt = 16;
        int s = 0;
        float e = -1e30f;
        bool valid = ci < ncnt;
        if (valid) {
            s = csr_src[start + j0 + ci];
            e = lrelu(asrc[s * HEADS + hd] + ad);
        }
        // chunk max within 16-lane head group
        float cmax = e;
#pragma unroll
        for (int off = 8; off >= 1; off >>= 1) cmax = fmaxf(cmax, __shfl_xor(cmax, off));
        float mnew = fmaxf(m, cmax);
        float fac = __expf(m - mnew);     // ==1.0 when unchanged
        ax *= fac; ay *= fac; dsum *= fac;
        m = mnew;
        float pe = valid ? __expf(e - m) : 0.f;
        dsum += pe;
#pragma unroll
        for (int jj = 0; jj < 16; jj++) {
            int mn = jj < ncnt ? jj : ncnt - 1;          // clamp: dup loads hit L1
            int sj = __builtin_amdgcn_readlane(s, mn);   // wave-uniform src id
            float pej = __shfl(pe, jj, 16);              // 0 for OOB jj
            float2 hj = h2[(size_t)sj * 64 + hd * 16 + ci];
            ax += pej * hj.x;
            ay += pej * hj.y;
        }
    }
#pragma unroll
    for (int off = 8; off >= 1; off >>= 1) dsum += __shfl_xor(dsum, off);
    float ps = __expf(e_self - m);
    float2 hv = h2[(size_t)d * 64 + hd * 16 + ci];
    ax += ps * hv.x;
    ay += ps * hv.y;
    float inv = 1.f / (dsum + ps + 1e-16f);
    ax *= inv; ay *= inv;

    // head mean: lanes l, l^16, l^32, l^48 hold same channel pair across heads
    ax += __shfl_xor(ax, 16); ax += __shfl_xor(ax, 32);
    ay += __shfl_xor(ay, 16); ay += __shfl_xor(ay, 32);
    if (hd == 0) {
        float2 bv = *(const float2*)&bias[2 * ci];
        float ox = 0.25f * ax + bv.x;
        float oy = 0.25f * ay + bv.y;
        float2 o;
        o.x = ox > 0.f ? ox : 0.f;
        o.y = oy > 0.f ? oy : 0.f;
        *(float2*)&xout[(size_t)d * HID + 2 * ci] = o;
    }
}

// ---------------- pooling + MLP ----------------

__global__ void pool_sum(const float* __restrict__ x, int n, float* __restrict__ g) {
    __shared__ float sm[256];
    int t = threadIdx.x;
    int c = t & 31;
    int r = t >> 5;   // 8 node-rows per block
    float acc = 0.f;
    for (int i = blockIdx.x * 8 + r; i < n; i += gridDim.x * 8)
        acc += x[(size_t)i * HID + c];
    sm[t] = acc;
    __syncthreads();
    if (t < 32) {
        float v = 0.f;
#pragma unroll
        for (int k = 0; k < 8; k++) v += sm[t + 32 * k];
        atomicAdd(&g[t], v);
    }
}

__global__ void mlp_final(const float* __restrict__ g,
                          const float* __restrict__ lw1, const float* __restrict__ lb1,
                          const float* __restrict__ lw2, const float* __restrict__ lb2,
                          float* __restrict__ out, float invn) {
    __shared__ float gm[32];
    int t = threadIdx.x;
    if (t < 32) gm[t] = g[t] * invn;
    __syncthreads();
    float q = 0.f;
    if (t < 16) {
        q = lb1[t];
        for (int c = 0; c < 32; c++) q += gm[c] * lw1[c * 16 + t];
        q = q > 0.f ? q : 0.f;
        q *= lw2[t];
    }
#pragma unroll
    for (int off = 8; off >= 1; off >>= 1) q += __shfl_xor(q, off);
    if (t == 0) out[0] = q + lb2[0];
}

// ---------------- launch ----------------

extern "C" void kernel_launch(void* const* d_in, const int* in_sizes, int n_in,
                              void* d_out, int out_size, void* d_ws, size_t ws_size,
                              hipStream_t stream) {
    const float* x   = (const float*)d_in[0];
    const int*   ei  = (const int*)d_in[1];
    const float* W1  = (const float*)d_in[2];
    const float* as1 = (const float*)d_in[3];
    const float* ad1 = (const float*)d_in[4];
    const float* b1  = (const float*)d_in[5];
    const float* W2  = (const float*)d_in[6];
    const float* as2 = (const float*)d_in[7];
    const float* ad2 = (const float*)d_in[8];
    const float* b2  = (const float*)d_in[9];
    const float* W3  = (const float*)d_in[10];
    const float* as3 = (const float*)d_in[11];
    const float* ad3 = (const float*)d_in[12];
    const float* b3  = (const float*)d_in[13];
    const float* lw1 = (const float*)d_in[14];
    const float* lb1 = (const float*)d_in[15];
    const float* lw2 = (const float*)d_in[16];
    const float* lb2 = (const float*)d_in[17];
    float* out = (float*)d_out;

    int n = in_sizes[0] / 128;   // 100000
    int E = in_sizes[1] / 2;     // 1600000
    int B = (n + 255) / 256;

    // workspace carve (256B aligned)
    char* p = (char*)d_ws;
    auto alloc = [&](size_t bytes) -> void* {
        void* r = (void*)p;
        p += (bytes + 255) & ~(size_t)255;
        return r;
    };
    int* deg       = (int*)alloc((size_t)n * 4);
    int* row_start = (int*)alloc((size_t)n * 4);
    int* cursor    = (int*)alloc((size_t)n * 4);
    int* partial   = (int*)alloc((size_t)B * 4);
    int* csr       = (int*)alloc((size_t)E * 4);
    float* asrc    = (float*)alloc((size_t)n * HEADS * 4);
    float* adst    = (float*)alloc((size_t)n * HEADS * 4);
    float* h       = (float*)alloc((size_t)n * F_HID * 4);
    float* xA      = (float*)alloc((size_t)n * HID * 4);
    float* xB      = (float*)alloc((size_t)n * HID * 4);
    float* g       = (float*)alloc(32 * 4);

    // CSR build (shared across all 3 layers)
    hipMemsetAsync(deg, 0, (size_t)n * 4, stream);
    deg_hist<<<(E + 255) / 256, 256, 0, stream>>>(ei, E, deg);
    scan_partial<<<B, 256, 0, stream>>>(deg, n, partial);
    scan_exclusive<<<1, 512, 0, stream>>>(partial, B);
    scan_final<<<B, 256, 0, stream>>>(deg, n, partial, row_start, cursor);
    scatter_edges<<<(E + 255) / 256, 256, 0, stream>>>(ei, E, cursor, csr);

    int gb = (n + 31) / 32;
    int ggb = (n + 3) / 4;

    // layer 1
    gemm_h<128><<<gb, 256, 0, stream>>>(x, W1, as1, ad1, h, asrc, adst, n);
    aggregate<<<ggb, 256, 0, stream>>>((const float2*)h, asrc, adst, row_start, deg, csr, b1, xA, n);

    // layer 2
    gemm_h<32><<<gb, 256, 0, stream>>>(xA, W2, as2, ad2, h, asrc, adst, n);
    aggregate<<<ggb, 256, 0, stream>>>((const float2*)h, asrc, adst, row_start, deg, csr, b2, xB, n);

    // layer 3
    gemm_h<32><<<gb, 256, 0, stream>>>(xB, W3, as3, ad3, h, asrc, adst, n);
    aggregate<<<ggb, 256, 0, stream>>>((const float2*)h, asrc, adst, row_start, deg, csr, b3, xA, n);

    // pooling + MLP
    hipMemsetAsync(g, 0, 32 * 4, stream);
    pool_sum<<<256, 256, 0, stream>>>(xA, n, g);
    mlp_final<<<1, 64, 0, stream>>>(g, lw1, lb1, lw2, lb2, out, 1.0f / (float)n);
}

// Round 4
// 688.133 us; speedup vs baseline: 1.9049x; 1.2069x over previous
//
#include <hip/hip_runtime.h>
#include <hip/hip_bf16.h>

// GAT (3-layer, HEADS=4, HID=32, concat=False head-mean) + global mean pool + MLP.
// R4: h stored as packed bf16x2 (u32/lane) -> gather traffic halved (256 B/edge),
//     int-only unpack, SGPR-base addressing in gather. Softmax accum stays f32;
//     asrc/adst from f32 accumulators in gemm epilogue.

#define HEADS 4
#define HID 32
#define F_HID 128   // HEADS*HID
#define NEG_SLOPE 0.2f

__device__ __forceinline__ float lrelu(float v) { return v > 0.f ? v : NEG_SLOPE * v; }

__device__ __forceinline__ uint32_t bf16_rne(float f) {
    union { float f; uint32_t u; } c; c.f = f;
    return (c.u + 0x7fffu + ((c.u >> 16) & 1u)) >> 16;
}
__device__ __forceinline__ float bf16_lo(uint32_t u) {
    union { uint32_t u; float f; } c; c.u = u << 16; return c.f;
}
__device__ __forceinline__ float bf16_hi(uint32_t u) {
    union { uint32_t u; float f; } c; c.u = u & 0xffff0000u; return c.f;
}

// ---------------- CSR build ----------------

__global__ void deg_hist(const int* __restrict__ ei, int E, int* __restrict__ deg) {
    int i = blockIdx.x * blockDim.x + threadIdx.x;
    if (i < E) {
        int d = ei[E + i];          // dst row of edge_index
        atomicAdd(&deg[d], 1);
    }
}

__global__ void scan_partial(const int* __restrict__ deg, int n, int* __restrict__ partial) {
    __shared__ int sm[256];
    int t = threadIdx.x;
    int i = blockIdx.x * 256 + t;
    sm[t] = (i < n) ? deg[i] : 0;
    __syncthreads();
    for (int s = 128; s > 0; s >>= 1) {
        if (t < s) sm[t] += sm[t + s];
        __syncthreads();
    }
    if (t == 0) partial[blockIdx.x] = sm[0];
}

__global__ __launch_bounds__(512) void scan_exclusive(int* partial, int B) {
    __shared__ int sm[512];
    int t = threadIdx.x;
    int carry = 0;
    for (int base = 0; base < B; base += 512) {
        int v = (base + t < B) ? partial[base + t] : 0;
        sm[t] = v;
        __syncthreads();
        for (int s = 1; s < 512; s <<= 1) {
            int add = (t >= s) ? sm[t - s] : 0;
            __syncthreads();
            sm[t] += add;
            __syncthreads();
        }
        if (base + t < B) partial[base + t] = carry + sm[t] - v;
        carry += sm[511];
        __syncthreads();
    }
}

__global__ void scan_final(const int* __restrict__ deg, int n, const int* __restrict__ partial,
                           int* __restrict__ row_start, int* __restrict__ cursor) {
    __shared__ int sm[256];
    int t = threadIdx.x;
    int i = blockIdx.x * 256 + t;
    int v = (i < n) ? deg[i] : 0;
    sm[t] = v;
    __syncthreads();
    for (int s = 1; s < 256; s <<= 1) {
        int add = (t >= s) ? sm[t - s] : 0;
        __syncthreads();
        sm[t] += add;
        __syncthreads();
    }
    if (i < n) {
        int excl = partial[blockIdx.x] + sm[t] - v;
        row_start[i] = excl;
        cursor[i] = excl;
    }
}

__global__ void scatter_edges(const int* __restrict__ ei, int E,
                              int* __restrict__ cursor, int* __restrict__ csr_src) {
    int i = blockIdx.x * blockDim.x + threadIdx.x;
    if (i < E) {
        int s = ei[i];
        int d = ei[E + i];
        int pos = atomicAdd(&cursor[d], 1);
        csr_src[pos] = s;
    }
}

// ---------------- per-layer kernels ----------------

// h = x @ W ([N,FIN] @ [FIN,128]) with fused alpha epilogue; h written as bf16x2.
// 32 nodes per 256-thread block; x-tile in LDS (float4 reads). Thread = 2 cols x 8 nodes.
template <int FIN>
__global__ __launch_bounds__(256) void gemm_h(const float* __restrict__ x,
                                              const float* __restrict__ W,
                                              const float* __restrict__ a_s,
                                              const float* __restrict__ a_d,
                                              uint32_t* __restrict__ hb,
                                              float* __restrict__ asrc,
                                              float* __restrict__ adst, int n) {
    constexpr int NPB = 32;
    __shared__ float xs[NPB * FIN];
    int t = threadIdx.x;
    int base = blockIdx.x * NPB;
    int nn = n - base; if (nn > NPB) nn = NPB;

    {   // stage x tile (float4)
        const float4* xg = (const float4*)(x + (size_t)base * FIN);
        float4* xs4 = (float4*)xs;
        int tot4 = nn * FIN / 4;
        for (int i = t; i < tot4; i += 256) xs4[i] = xg[i];
        for (int i = tot4 * 4 + t; i < NPB * FIN; i += 256) xs[i] = 0.f;
    }
    __syncthreads();

    int grp = t >> 6;       // 0..3, each grp = one wave, 8 nodes
    int l = t & 63;
    int col0 = l * 2;

    float2 acc[8];
#pragma unroll
    for (int j = 0; j < 8; j++) { acc[j].x = 0.f; acc[j].y = 0.f; }

    for (int k4 = 0; k4 < FIN; k4 += 4) {
        float4 xv[8];
#pragma unroll
        for (int j = 0; j < 8; j++)
            xv[j] = *(const float4*)&xs[(grp * 8 + j) * FIN + k4];
#pragma unroll
        for (int kk = 0; kk < 4; kk++) {
            float2 wv = *(const float2*)&W[(size_t)(k4 + kk) * F_HID + col0];
#pragma unroll
            for (int j = 0; j < 8; j++) {
                float xk = (&xv[j].x)[kk];
                acc[j].x += xk * wv.x;
                acc[j].y += xk * wv.y;
            }
        }
    }

    float ws0 = a_s[col0], ws1 = a_s[col0 + 1];
    float wd0 = a_d[col0], wd1 = a_d[col0 + 1];
#pragma unroll
    for (int j = 0; j < 8; j++) {
        int node = base + grp * 8 + j;
        bool ok = node < n;
        if (ok)
            hb[((size_t)node << 6) + l] = bf16_rne(acc[j].x) | (bf16_rne(acc[j].y) << 16);
        float vs = acc[j].x * ws0 + acc[j].y * ws1;
        float vd = acc[j].x * wd0 + acc[j].y * wd1;
#pragma unroll
        for (int off = 8; off >= 1; off >>= 1) {
            vs += __shfl_xor(vs, off);
            vd += __shfl_xor(vd, off);
        }
        if (ok && (l & 15) == 0) {
            int hd = l >> 4;
            asrc[node * HEADS + hd] = vs;
            adst[node * HEADS + hd] = vd;
        }
    }
}

// Wave-per-node single-pass online-softmax aggregate over bf16x2 h.
// lane l: hd = l>>4 (head), ci = l&15 (channel pair within head); h pair index == l.
__global__ __launch_bounds__(256) void aggregate(const uint32_t* __restrict__ hb,
                                                 const float* __restrict__ asrc,
                                                 const float* __restrict__ adst,
                                                 const int* __restrict__ row_start,
                                                 const int* __restrict__ deg,
                                                 const int* __restrict__ csr_src,
                                                 const float* __restrict__ bias,
                                                 float* __restrict__ xout, int n) {
    int d = blockIdx.x * 4 + (threadIdx.x >> 6);
    if (d >= n) return;
    int l = threadIdx.x & 63;
    int hd = l >> 4;
    int ci = l & 15;
    int start = row_start[d];
    int cnt = deg[d];
    float ad = adst[d * HEADS + hd];
    float e_self = lrelu(asrc[d * HEADS + hd] + ad);

    float m = e_self;
    float dsum = 0.f;
    float ax = 0.f, ay = 0.f;

    for (int j0 = 0; j0 < cnt; j0 += 16) {
        int ncnt = cnt - j0; if (ncnt > 16) ncnt = 16;
        int s = 0;
        float e = -1e30f;
        bool valid = ci < ncnt;
        if (valid) {
            s = csr_src[start + j0 + ci];
            e = lrelu(asrc[s * HEADS + hd] + ad);
        }
        // chunk max within 16-lane head group
        float cmax = e;
#pragma unroll
        for (int off = 8; off >= 1; off >>= 1) cmax = fmaxf(cmax, __shfl_xor(cmax, off));
        float mnew = fmaxf(m, cmax);
        float fac = __expf(m - mnew);     // ==1.0 when unchanged
        ax *= fac; ay *= fac; dsum *= fac;
        m = mnew;
        float pe = valid ? __expf(e - m) : 0.f;
        dsum += pe;
#pragma unroll
        for (int jj = 0; jj < 16; jj++) {
            int mn = jj < ncnt ? jj : ncnt - 1;          // uniform clamp (SALU)
            int sj = __builtin_amdgcn_readlane(s, mn);   // wave-uniform src id (SGPR)
            float pej = __shfl(pe, jj, 16);              // 0 for OOB jj
            const uint32_t* hrow = hb + ((size_t)sj << 6);   // SGPR base
            uint32_t u = hrow[l];                            // voffset = l*4
            ax = fmaf(pej, bf16_lo(u), ax);
            ay = fmaf(pej, bf16_hi(u), ay);
        }
    }
#pragma unroll
    for (int off = 8; off >= 1; off >>= 1) dsum += __shfl_xor(dsum, off);
    float ps = __expf(e_self - m);
    uint32_t us = hb[((size_t)d << 6) + l];
    ax = fmaf(ps, bf16_lo(us), ax);
    ay = fmaf(ps, bf16_hi(us), ay);
    float inv = 1.f / (dsum + ps + 1e-16f);
    ax *= inv; ay *= inv;

    // head mean: lanes l, l^16, l^32, l^48 hold same channel pair across heads
    ax += __shfl_xor(ax, 16); ax += __shfl_xor(ax, 32);
    ay += __shfl_xor(ay, 16); ay += __shfl_xor(ay, 32);
    if (hd == 0) {
        float2 bv = *(const float2*)&bias[2 * ci];
        float ox = 0.25f * ax + bv.x;
        float oy = 0.25f * ay + bv.y;
        float2 o;
        o.x = ox > 0.f ? ox : 0.f;
        o.y = oy > 0.f ? oy : 0.f;
        *(float2*)&xout[(size_t)d * HID + 2 * ci] = o;
    }
}

// ---------------- pooling + MLP ----------------

__global__ void pool_sum(const float* __restrict__ x, int n, float* __restrict__ g) {
    __shared__ float sm[256];
    int t = threadIdx.x;
    int c = t & 31;
    int r = t >> 5;   // 8 node-rows per block
    float acc = 0.f;
    for (int i = blockIdx.x * 8 + r; i < n; i += gridDim.x * 8)
        acc += x[(size_t)i * HID + c];
    sm[t] = acc;
    __syncthreads();
    if (t < 32) {
        float v = 0.f;
#pragma unroll
        for (int k = 0; k < 8; k++) v += sm[t + 32 * k];
        atomicAdd(&g[t], v);
    }
}

__global__ void mlp_final(const float* __restrict__ g,
                          const float* __restrict__ lw1, const float* __restrict__ lb1,
                          const float* __restrict__ lw2, const float* __restrict__ lb2,
                          float* __restrict__ out, float invn) {
    __shared__ float gm[32];
    int t = threadIdx.x;
    if (t < 32) gm[t] = g[t] * invn;
    __syncthreads();
    float q = 0.f;
    if (t < 16) {
        q = lb1[t];
        for (int c = 0; c < 32; c++) q += gm[c] * lw1[c * 16 + t];
        q = q > 0.f ? q : 0.f;
        q *= lw2[t];
    }
#pragma unroll
    for (int off = 8; off >= 1; off >>= 1) q += __shfl_xor(q, off);
    if (t == 0) out[0] = q + lb2[0];
}

// ---------------- launch ----------------

extern "C" void kernel_launch(void* const* d_in, const int* in_sizes, int n_in,
                              void* d_out, int out_size, void* d_ws, size_t ws_size,
                              hipStream_t stream) {
    const float* x   = (const float*)d_in[0];
    const int*   ei  = (const int*)d_in[1];
    const float* W1  = (const float*)d_in[2];
    const float* as1 = (const float*)d_in[3];
    const float* ad1 = (const float*)d_in[4];
    const float* b1  = (const float*)d_in[5];
    const float* W2  = (const float*)d_in[6];
    const float* as2 = (const float*)d_in[7];
    const float* ad2 = (const float*)d_in[8];
    const float* b2  = (const float*)d_in[9];
    const float* W3  = (const float*)d_in[10];
    const float* as3 = (const float*)d_in[11];
    const float* ad3 = (const float*)d_in[12];
    const float* b3  = (const float*)d_in[13];
    const float* lw1 = (const float*)d_in[14];
    const float* lb1 = (const float*)d_in[15];
    const float* lw2 = (const float*)d_in[16];
    const float* lb2 = (const float*)d_in[17];
    float* out = (float*)d_out;

    int n = in_sizes[0] / 128;   // 100000
    int E = in_sizes[1] / 2;     // 1600000
    int B = (n + 255) / 256;

    // workspace carve (256B aligned)
    char* p = (char*)d_ws;
    auto alloc = [&](size_t bytes) -> void* {
        void* r = (void*)p;
        p += (bytes + 255) & ~(size_t)255;
        return r;
    };
    int* deg       = (int*)alloc((size_t)n * 4);
    int* row_start = (int*)alloc((size_t)n * 4);
    int* cursor    = (int*)alloc((size_t)n * 4);
    int* partial   = (int*)alloc((size_t)B * 4);
    int* csr       = (int*)alloc((size_t)E * 4);
    float* asrc    = (float*)alloc((size_t)n * HEADS * 4);
    float* adst    = (float*)alloc((size_t)n * HEADS * 4);
    uint32_t* hb   = (uint32_t*)alloc((size_t)n * 64 * 4);   // bf16x2 packed h
    float* xA      = (float*)alloc((size_t)n * HID * 4);
    float* xB      = (float*)alloc((size_t)n * HID * 4);
    float* g       = (float*)alloc(32 * 4);

    // CSR build (shared across all 3 layers)
    hipMemsetAsync(deg, 0, (size_t)n * 4, stream);
    deg_hist<<<(E + 255) / 256, 256, 0, stream>>>(ei, E, deg);
    scan_partial<<<B, 256, 0, stream>>>(deg, n, partial);
    scan_exclusive<<<1, 512, 0, stream>>>(partial, B);
    scan_final<<<B, 256, 0, stream>>>(deg, n, partial, row_start, cursor);
    scatter_edges<<<(E + 255) / 256, 256, 0, stream>>>(ei, E, cursor, csr);

    int gb = (n + 31) / 32;
    int ggb = (n + 3) / 4;

    // layer 1
    gemm_h<128><<<gb, 256, 0, stream>>>(x, W1, as1, ad1, hb, asrc, adst, n);
    aggregate<<<ggb, 256, 0, stream>>>(hb, asrc, adst, row_start, deg, csr, b1, xA, n);

    // layer 2
    gemm_h<32><<<gb, 256, 0, stream>>>(xA, W2, as2, ad2, hb, asrc, adst, n);
    aggregate<<<ggb, 256, 0, stream>>>(hb, asrc, adst, row_start, deg, csr, b2, xB, n);

    // layer 3
    gemm_h<32><<<gb, 256, 0, stream>>>(xB, W3, as3, ad3, hb, asrc, adst, n);
    aggregate<<<ggb, 256, 0, stream>>>(hb, asrc, adst, row_start, deg, csr, b3, xA, n);

    // pooling + MLP
    hipMemsetAsync(g, 0, 32 * 4, stream);
    pool_sum<<<256, 256, 0, stream>>>(xA, n, g);
    mlp_final<<<1, 64, 0, stream>>>(g, lw1, lb1, lw2, lb2, out, 1.0f / (float)n);
}

// Round 5
// 621.046 us; speedup vs baseline: 2.1107x; 1.1080x over previous
//
#include <hip/hip_runtime.h>
#include <hip/hip_bf16.h>

// GAT (3-layer, HEADS=4, HID=32, concat=False head-mean) + global mean pool + MLP.
// R5: CSR build rework — random 4B scatter (105 MB line-granular writeback) replaced
//     by two-level bucket sort: LDS-histogram bucket scatter (contiguous per-block
//     runs, packed (src<<5)|dstlo) + per-bucket exact placement seeded from row_start.

#define HEADS 4
#define HID 32
#define F_HID 128   // HEADS*HID
#define NEG_SLOPE 0.2f
#define BSHIFT 5
#define MAXB 3328   // max buckets supported (n <= 106496)

__device__ __forceinline__ float lrelu(float v) { return v > 0.f ? v : NEG_SLOPE * v; }

__device__ __forceinline__ uint32_t bf16_rne(float f) {
    union { float f; uint32_t u; } c; c.f = f;
    return (c.u + 0x7fffu + ((c.u >> 16) & 1u)) >> 16;
}
__device__ __forceinline__ float bf16_lo(uint32_t u) {
    union { uint32_t u; float f; } c; c.u = u << 16; return c.f;
}
__device__ __forceinline__ float bf16_hi(uint32_t u) {
    union { uint32_t u; float f; } c; c.u = u & 0xffff0000u; return c.f;
}

// ---------------- CSR build ----------------

__global__ void deg_hist(const int* __restrict__ ei, int E, int* __restrict__ deg) {
    int i = blockIdx.x * blockDim.x + threadIdx.x;
    if (i < E) {
        int d = ei[E + i];          // dst row of edge_index
        atomicAdd(&deg[d], 1);
    }
}

__global__ void scan_partial(const int* __restrict__ deg, int n, int* __restrict__ partial) {
    __shared__ int sm[256];
    int t = threadIdx.x;
    int i = blockIdx.x * 256 + t;
    sm[t] = (i < n) ? deg[i] : 0;
    __syncthreads();
    for (int s = 128; s > 0; s >>= 1) {
        if (t < s) sm[t] += sm[t + s];
        __syncthreads();
    }
    if (t == 0) partial[blockIdx.x] = sm[0];
}

__global__ __launch_bounds__(512) void scan_exclusive(int* partial, int B) {
    __shared__ int sm[512];
    int t = threadIdx.x;
    int carry = 0;
    for (int base = 0; base < B; base += 512) {
        int v = (base + t < B) ? partial[base + t] : 0;
        sm[t] = v;
        __syncthreads();
        for (int s = 1; s < 512; s <<= 1) {
            int add = (t >= s) ? sm[t - s] : 0;
            __syncthreads();
            sm[t] += add;
            __syncthreads();
        }
        if (base + t < B) partial[base + t] = carry + sm[t] - v;
        carry += sm[511];
        __syncthreads();
    }
}

__global__ void scan_final(const int* __restrict__ deg, int n, const int* __restrict__ partial,
                           int* __restrict__ row_start) {
    __shared__ int sm[256];
    int t = threadIdx.x;
    int i = blockIdx.x * 256 + t;
    int v = (i < n) ? deg[i] : 0;
    sm[t] = v;
    __syncthreads();
    for (int s = 1; s < 256; s <<= 1) {
        int add = (t >= s) ? sm[t - s] : 0;
        __syncthreads();
        sm[t] += add;
        __syncthreads();
    }
    if (i < n) row_start[i] = partial[blockIdx.x] + sm[t] - v;
}

__global__ void init_gcursor(const int* __restrict__ row_start, int n, int nb,
                             int* __restrict__ gcursor) {
    int b = blockIdx.x * 256 + threadIdx.x;
    if (b < nb) gcursor[b] = row_start[b << BSHIFT];
}

// Phase B: scatter edges into 32-node buckets; per-block contiguous runs.
__global__ __launch_bounds__(512) void bucket_scatter(const int* __restrict__ ei, int E, int nb,
                                                      int* __restrict__ gcursor,
                                                      uint32_t* __restrict__ tmp) {
    __shared__ int hist[MAXB];
    __shared__ int base[MAXB];
    int t = threadIdx.x;
    int per = (E + gridDim.x - 1) / gridDim.x;
    int e0 = blockIdx.x * per;
    int e1 = e0 + per; if (e1 > E) e1 = E;

    for (int i = t; i < nb; i += 512) hist[i] = 0;
    __syncthreads();
    for (int i = e0 + t; i < e1; i += 512) {
        int d = ei[E + i];
        atomicAdd(&hist[d >> BSHIFT], 1);
    }
    __syncthreads();
    for (int i = t; i < nb; i += 512) {
        int c = hist[i];
        base[i] = c ? atomicAdd(&gcursor[i], c) : 0;
        hist[i] = 0;   // reuse as local cursor
    }
    __syncthreads();
    for (int i = e0 + t; i < e1; i += 512) {
        int d = ei[E + i];
        int s = ei[i];
        int b = d >> BSHIFT;
        int loc = atomicAdd(&hist[b], 1);
        tmp[base[b] + loc] = ((uint32_t)s << BSHIFT) | (uint32_t)(d & 31);
    }
}

// Phase C: per-bucket exact placement (positions seeded from row_start — no recount).
__global__ __launch_bounds__(256) void bucket_sort(const uint32_t* __restrict__ tmp,
                                                   const int* __restrict__ row_start,
                                                   int n, int E,
                                                   int* __restrict__ csr) {
    __shared__ int cur[32];
    int b = blockIdx.x;
    int node0 = b << BSHIFT;
    int base = row_start[node0];
    int node1 = node0 + 32;
    int end = (node1 < n) ? row_start[node1] : E;
    int cnt = end - base;
    int t = threadIdx.x;
    if (t < 32) {
        int nd = node0 + t;
        cur[t] = (nd < n) ? (row_start[nd] - base) : 0;
    }
    __syncthreads();
    for (int i = t; i < cnt; i += 256) {
        uint32_t v = tmp[base + i];
        int pos = atomicAdd(&cur[v & 31], 1);
        csr[base + pos] = (int)(v >> BSHIFT);
    }
}

// ---------------- per-layer kernels ----------------

// h = x @ W ([N,FIN] @ [FIN,128]) with fused alpha epilogue; h written as bf16x2.
template <int FIN>
__global__ __launch_bounds__(256) void gemm_h(const float* __restrict__ x,
                                              const float* __restrict__ W,
                                              const float* __restrict__ a_s,
                                              const float* __restrict__ a_d,
                                              uint32_t* __restrict__ hb,
                                              float* __restrict__ asrc,
                                              float* __restrict__ adst, int n) {
    constexpr int NPB = 32;
    __shared__ float xs[NPB * FIN];
    int t = threadIdx.x;
    int base = blockIdx.x * NPB;
    int nn = n - base; if (nn > NPB) nn = NPB;

    {   // stage x tile (float4)
        const float4* xg = (const float4*)(x + (size_t)base * FIN);
        float4* xs4 = (float4*)xs;
        int tot4 = nn * FIN / 4;
        for (int i = t; i < tot4; i += 256) xs4[i] = xg[i];
        for (int i = tot4 * 4 + t; i < NPB * FIN; i += 256) xs[i] = 0.f;
    }
    __syncthreads();

    int grp = t >> 6;       // 0..3, each grp = one wave, 8 nodes
    int l = t & 63;
    int col0 = l * 2;

    float2 acc[8];
#pragma unroll
    for (int j = 0; j < 8; j++) { acc[j].x = 0.f; acc[j].y = 0.f; }

    for (int k4 = 0; k4 < FIN; k4 += 4) {
        float4 xv[8];
#pragma unroll
        for (int j = 0; j < 8; j++)
            xv[j] = *(const float4*)&xs[(grp * 8 + j) * FIN + k4];
#pragma unroll
        for (int kk = 0; kk < 4; kk++) {
            float2 wv = *(const float2*)&W[(size_t)(k4 + kk) * F_HID + col0];
#pragma unroll
            for (int j = 0; j < 8; j++) {
                float xk = (&xv[j].x)[kk];
                acc[j].x += xk * wv.x;
                acc[j].y += xk * wv.y;
            }
        }
    }

    float ws0 = a_s[col0], ws1 = a_s[col0 + 1];
    float wd0 = a_d[col0], wd1 = a_d[col0 + 1];
#pragma unroll
    for (int j = 0; j < 8; j++) {
        int node = base + grp * 8 + j;
        bool ok = node < n;
        if (ok)
            hb[((size_t)node << 6) + l] = bf16_rne(acc[j].x) | (bf16_rne(acc[j].y) << 16);
        float vs = acc[j].x * ws0 + acc[j].y * ws1;
        float vd = acc[j].x * wd0 + acc[j].y * wd1;
#pragma unroll
        for (int off = 8; off >= 1; off >>= 1) {
            vs += __shfl_xor(vs, off);
            vd += __shfl_xor(vd, off);
        }
        if (ok && (l & 15) == 0) {
            int hd = l >> 4;
            asrc[node * HEADS + hd] = vs;
            adst[node * HEADS + hd] = vd;
        }
    }
}

// Wave-per-node single-pass online-softmax aggregate over bf16x2 h.
__global__ __launch_bounds__(256) void aggregate(const uint32_t* __restrict__ hb,
                                                 const float* __restrict__ asrc,
                                                 const float* __restrict__ adst,
                                                 const int* __restrict__ row_start,
                                                 const int* __restrict__ deg,
                                                 const int* __restrict__ csr_src,
                                                 const float* __restrict__ bias,
                                                 float* __restrict__ xout, int n) {
    int d = blockIdx.x * 4 + (threadIdx.x >> 6);
    if (d >= n) return;
    int l = threadIdx.x & 63;
    int hd = l >> 4;
    int ci = l & 15;
    int start = row_start[d];
    int cnt = deg[d];
    float ad = adst[d * HEADS + hd];
    float e_self = lrelu(asrc[d * HEADS + hd] + ad);

    float m = e_self;
    float dsum = 0.f;
    float ax = 0.f, ay = 0.f;

    for (int j0 = 0; j0 < cnt; j0 += 16) {
        int ncnt = cnt - j0; if (ncnt > 16) ncnt = 16;
        int s = 0;
        float e = -1e30f;
        bool valid = ci < ncnt;
        if (valid) {
            s = csr_src[start + j0 + ci];
            e = lrelu(asrc[s * HEADS + hd] + ad);
        }
        float cmax = e;
#pragma unroll
        for (int off = 8; off >= 1; off >>= 1) cmax = fmaxf(cmax, __shfl_xor(cmax, off));
        float mnew = fmaxf(m, cmax);
        float fac = __expf(m - mnew);     // ==1.0 when unchanged
        ax *= fac; ay *= fac; dsum *= fac;
        m = mnew;
        float pe = valid ? __expf(e - m) : 0.f;
        dsum += pe;
#pragma unroll
        for (int jj = 0; jj < 16; jj++) {
            int mn = jj < ncnt ? jj : ncnt - 1;          // uniform clamp (SALU)
            int sj = __builtin_amdgcn_readlane(s, mn);   // wave-uniform src id (SGPR)
            float pej = __shfl(pe, jj, 16);              // 0 for OOB jj
            const uint32_t* hrow = hb + ((size_t)sj << 6);   // SGPR base
            uint32_t u = hrow[l];                            // voffset = l*4
            ax = fmaf(pej, bf16_lo(u), ax);
            ay = fmaf(pej, bf16_hi(u), ay);
        }
    }
#pragma unroll
    for (int off = 8; off >= 1; off >>= 1) dsum += __shfl_xor(dsum, off);
    float ps = __expf(e_self - m);
    uint32_t us = hb[((size_t)d << 6) + l];
    ax = fmaf(ps, bf16_lo(us), ax);
    ay = fmaf(ps, bf16_hi(us), ay);
    float inv = 1.f / (dsum + ps + 1e-16f);
    ax *= inv; ay *= inv;

    // head mean across lanes l, l^16, l^32, l^48
    ax += __shfl_xor(ax, 16); ax += __shfl_xor(ax, 32);
    ay += __shfl_xor(ay, 16); ay += __shfl_xor(ay, 32);
    if (hd == 0) {
        float2 bv = *(const float2*)&bias[2 * ci];
        float ox = 0.25f * ax + bv.x;
        float oy = 0.25f * ay + bv.y;
        float2 o;
        o.x = ox > 0.f ? ox : 0.f;
        o.y = oy > 0.f ? oy : 0.f;
        *(float2*)&xout[(size_t)d * HID + 2 * ci] = o;
    }
}

// ---------------- pooling + MLP ----------------

__global__ void pool_sum(const float* __restrict__ x, int n, float* __restrict__ g) {
    __shared__ float sm[256];
    int t = threadIdx.x;
    int c = t & 31;
    int r = t >> 5;   // 8 node-rows per block
    float acc = 0.f;
    for (int i = blockIdx.x * 8 + r; i < n; i += gridDim.x * 8)
        acc += x[(size_t)i * HID + c];
    sm[t] = acc;
    __syncthreads();
    if (t < 32) {
        float v = 0.f;
#pragma unroll
        for (int k = 0; k < 8; k++) v += sm[t + 32 * k];
        atomicAdd(&g[t], v);
    }
}

__global__ void mlp_final(const float* __restrict__ g,
                          const float* __restrict__ lw1, const float* __restrict__ lb1,
                          const float* __restrict__ lw2, const float* __restrict__ lb2,
                          float* __restrict__ out, float invn) {
    __shared__ float gm[32];
    int t = threadIdx.x;
    if (t < 32) gm[t] = g[t] * invn;
    __syncthreads();
    float q = 0.f;
    if (t < 16) {
        q = lb1[t];
        for (int c = 0; c < 32; c++) q += gm[c] * lw1[c * 16 + t];
        q = q > 0.f ? q : 0.f;
        q *= lw2[t];
    }
#pragma unroll
    for (int off = 8; off >= 1; off >>= 1) q += __shfl_xor(q, off);
    if (t == 0) out[0] = q + lb2[0];
}

// ---------------- launch ----------------

extern "C" void kernel_launch(void* const* d_in, const int* in_sizes, int n_in,
                              void* d_out, int out_size, void* d_ws, size_t ws_size,
                              hipStream_t stream) {
    const float* x   = (const float*)d_in[0];
    const int*   ei  = (const int*)d_in[1];
    const float* W1  = (const float*)d_in[2];
    const float* as1 = (const float*)d_in[3];
    const float* ad1 = (const float*)d_in[4];
    const float* b1  = (const float*)d_in[5];
    const float* W2  = (const float*)d_in[6];
    const float* as2 = (const float*)d_in[7];
    const float* ad2 = (const float*)d_in[8];
    const float* b2  = (const float*)d_in[9];
    const float* W3  = (const float*)d_in[10];
    const float* as3 = (const float*)d_in[11];
    const float* ad3 = (const float*)d_in[12];
    const float* b3  = (const float*)d_in[13];
    const float* lw1 = (const float*)d_in[14];
    const float* lb1 = (const float*)d_in[15];
    const float* lw2 = (const float*)d_in[16];
    const float* lb2 = (const float*)d_in[17];
    float* out = (float*)d_out;

    int n = in_sizes[0] / 128;   // 100000
    int E = in_sizes[1] / 2;     // 1600000
    int B = (n + 255) / 256;
    int nb = (n + 31) >> BSHIFT; // 3125 buckets

    // workspace carve (256B aligned)
    char* p = (char*)d_ws;
    auto alloc = [&](size_t bytes) -> void* {
        void* r = (void*)p;
        p += (bytes + 255) & ~(size_t)255;
        return r;
    };
    int* deg       = (int*)alloc((size_t)n * 4);
    int* row_start = (int*)alloc((size_t)n * 4);
    int* gcursor   = (int*)alloc((size_t)nb * 4);
    int* partial   = (int*)alloc((size_t)B * 4);
    int* csr       = (int*)alloc((size_t)E * 4);
    uint32_t* tmp  = (uint32_t*)alloc((size_t)E * 4);
    float* asrc    = (float*)alloc((size_t)n * HEADS * 4);
    float* adst    = (float*)alloc((size_t)n * HEADS * 4);
    uint32_t* hb   = (uint32_t*)alloc((size_t)n * 64 * 4);   // bf16x2 packed h
    float* xA      = (float*)alloc((size_t)n * HID * 4);
    float* xB      = (float*)alloc((size_t)n * HID * 4);
    float* g       = (float*)alloc(32 * 4);

    // CSR build (shared across all 3 layers)
    hipMemsetAsync(deg, 0, (size_t)n * 4, stream);
    deg_hist<<<(E + 255) / 256, 256, 0, stream>>>(ei, E, deg);
    scan_partial<<<B, 256, 0, stream>>>(deg, n, partial);
    scan_exclusive<<<1, 512, 0, stream>>>(partial, B);
    scan_final<<<B, 256, 0, stream>>>(deg, n, partial, row_start);
    init_gcursor<<<(nb + 255) / 256, 256, 0, stream>>>(row_start, n, nb, gcursor);
    bucket_scatter<<<64, 512, 0, stream>>>(ei, E, nb, gcursor, tmp);
    bucket_sort<<<nb, 256, 0, stream>>>(tmp, row_start, n, E, csr);

    int gb = (n + 31) / 32;
    int ggb = (n + 3) / 4;

    // layer 1
    gemm_h<128><<<gb, 256, 0, stream>>>(x, W1, as1, ad1, hb, asrc, adst, n);
    aggregate<<<ggb, 256, 0, stream>>>(hb, asrc, adst, row_start, deg, csr, b1, xA, n);

    // layer 2
    gemm_h<32><<<gb, 256, 0, stream>>>(xA, W2, as2, ad2, hb, asrc, adst, n);
    aggregate<<<ggb, 256, 0, stream>>>(hb, asrc, adst, row_start, deg, csr, b2, xB, n);

    // layer 3
    gemm_h<32><<<gb, 256, 0, stream>>>(xB, W3, as3, ad3, hb, asrc, adst, n);
    aggregate<<<ggb, 256, 0, stream>>>(hb, asrc, adst, row_start, deg, csr, b3, xA, n);

    // pooling + MLP
    hipMemsetAsync(g, 0, 32 * 4, stream);
    pool_sum<<<256, 256, 0, stream>>>(xA, n, g);
    mlp_final<<<1, 64, 0, stream>>>(g, lw1, lb1, lw2, lb2, out, 1.0f / (float)n);
}

// Round 6
// 592.349 us; speedup vs baseline: 2.2129x; 1.0484x over previous
//
#include <hip/hip_runtime.h>
#include <hip/hip_bf16.h>

// GAT (3-layer, HEADS=4, HID=32, concat=False head-mean) + global mean pool + MLP.
// R6: aggregate rewritten — 4 edges gathered per global_load_dwordx4 (lane remap:
//     edge=4q+(l>>4), head=(l&15)>>2, u32quad=l&3; 16-lane group = one full 256B row),
//     fixed-pattern ds_bpermute for pe/src broadcast, v_pk_fma_f32 accumulation.

#define HEADS 4
#define HID 32
#define F_HID 128   // HEADS*HID
#define NEG_SLOPE 0.2f
#define BSHIFT 5
#define MAXB 3328   // max buckets supported (n <= 106496)

typedef float v2f __attribute__((ext_vector_type(2)));

__device__ __forceinline__ float lrelu(float v) { return v > 0.f ? v : NEG_SLOPE * v; }

__device__ __forceinline__ uint32_t bf16_rne(float f) {
    union { float f; uint32_t u; } c; c.f = f;
    return (c.u + 0x7fffu + ((c.u >> 16) & 1u)) >> 16;
}
__device__ __forceinline__ v2f up2(uint32_t u) {
    v2f r;
    r.x = __uint_as_float(u << 16);
    r.y = __uint_as_float(u & 0xffff0000u);
    return r;
}
__device__ __forceinline__ float bperm_f(int addr, float v) {
    return __int_as_float(__builtin_amdgcn_ds_bpermute(addr, __float_as_int(v)));
}
__device__ __forceinline__ v2f vshflxor(v2f v, int m) {
    v2f r; r.x = __shfl_xor(v.x, m); r.y = __shfl_xor(v.y, m); return r;
}

// ---------------- CSR build ----------------

__global__ void deg_hist(const int* __restrict__ ei, int E, int* __restrict__ deg) {
    int i = blockIdx.x * blockDim.x + threadIdx.x;
    if (i < E) {
        int d = ei[E + i];          // dst row of edge_index
        atomicAdd(&deg[d], 1);
    }
}

__global__ void scan_partial(const int* __restrict__ deg, int n, int* __restrict__ partial) {
    __shared__ int sm[256];
    int t = threadIdx.x;
    int i = blockIdx.x * 256 + t;
    sm[t] = (i < n) ? deg[i] : 0;
    __syncthreads();
    for (int s = 128; s > 0; s >>= 1) {
        if (t < s) sm[t] += sm[t + s];
        __syncthreads();
    }
    if (t == 0) partial[blockIdx.x] = sm[0];
}

__global__ __launch_bounds__(512) void scan_exclusive(int* partial, int B) {
    __shared__ int sm[512];
    int t = threadIdx.x;
    int carry = 0;
    for (int base = 0; base < B; base += 512) {
        int v = (base + t < B) ? partial[base + t] : 0;
        sm[t] = v;
        __syncthreads();
        for (int s = 1; s < 512; s <<= 1) {
            int add = (t >= s) ? sm[t - s] : 0;
            __syncthreads();
            sm[t] += add;
            __syncthreads();
        }
        if (base + t < B) partial[base + t] = carry + sm[t] - v;
        carry += sm[511];
        __syncthreads();
    }
}

__global__ void scan_final(const int* __restrict__ deg, int n, const int* __restrict__ partial,
                           int* __restrict__ row_start) {
    __shared__ int sm[256];
    int t = threadIdx.x;
    int i = blockIdx.x * 256 + t;
    int v = (i < n) ? deg[i] : 0;
    sm[t] = v;
    __syncthreads();
    for (int s = 1; s < 256; s <<= 1) {
        int add = (t >= s) ? sm[t - s] : 0;
        __syncthreads();
        sm[t] += add;
        __syncthreads();
    }
    if (i < n) row_start[i] = partial[blockIdx.x] + sm[t] - v;
}

__global__ void init_gcursor(const int* __restrict__ row_start, int n, int nb,
                             int* __restrict__ gcursor) {
    int b = blockIdx.x * 256 + threadIdx.x;
    if (b < nb) gcursor[b] = row_start[b << BSHIFT];
}

// Phase B: scatter edges into 32-node buckets; per-block contiguous runs.
__global__ __launch_bounds__(512) void bucket_scatter(const int* __restrict__ ei, int E, int nb,
                                                      int* __restrict__ gcursor,
                                                      uint32_t* __restrict__ tmp) {
    __shared__ int hist[MAXB];
    __shared__ int base[MAXB];
    int t = threadIdx.x;
    int per = (E + gridDim.x - 1) / gridDim.x;
    int e0 = blockIdx.x * per;
    int e1 = e0 + per; if (e1 > E) e1 = E;

    for (int i = t; i < nb; i += 512) hist[i] = 0;
    __syncthreads();
    for (int i = e0 + t; i < e1; i += 512) {
        int d = ei[E + i];
        atomicAdd(&hist[d >> BSHIFT], 1);
    }
    __syncthreads();
    for (int i = t; i < nb; i += 512) {
        int c = hist[i];
        base[i] = c ? atomicAdd(&gcursor[i], c) : 0;
        hist[i] = 0;   // reuse as local cursor
    }
    __syncthreads();
    for (int i = e0 + t; i < e1; i += 512) {
        int d = ei[E + i];
        int s = ei[i];
        int b = d >> BSHIFT;
        int loc = atomicAdd(&hist[b], 1);
        tmp[base[b] + loc] = ((uint32_t)s << BSHIFT) | (uint32_t)(d & 31);
    }
}

// Phase C: per-bucket exact placement (positions seeded from row_start — no recount).
__global__ __launch_bounds__(256) void bucket_sort(const uint32_t* __restrict__ tmp,
                                                   const int* __restrict__ row_start,
                                                   int n, int E,
                                                   int* __restrict__ csr) {
    __shared__ int cur[32];
    int b = blockIdx.x;
    int node0 = b << BSHIFT;
    int base = row_start[node0];
    int node1 = node0 + 32;
    int end = (node1 < n) ? row_start[node1] : E;
    int cnt = end - base;
    int t = threadIdx.x;
    if (t < 32) {
        int nd = node0 + t;
        cur[t] = (nd < n) ? (row_start[nd] - base) : 0;
    }
    __syncthreads();
    for (int i = t; i < cnt; i += 256) {
        uint32_t v = tmp[base + i];
        int pos = atomicAdd(&cur[v & 31], 1);
        csr[base + pos] = (int)(v >> BSHIFT);
    }
}

// ---------------- per-layer kernels ----------------

// h = x @ W ([N,FIN] @ [FIN,128]) with fused alpha epilogue; h written as bf16x2.
template <int FIN>
__global__ __launch_bounds__(256) void gemm_h(const float* __restrict__ x,
                                              const float* __restrict__ W,
                                              const float* __restrict__ a_s,
                                              const float* __restrict__ a_d,
                                              uint32_t* __restrict__ hb,
                                              float* __restrict__ asrc,
                                              float* __restrict__ adst, int n) {
    constexpr int NPB = 32;
    __shared__ float xs[NPB * FIN];
    int t = threadIdx.x;
    int base = blockIdx.x * NPB;
    int nn = n - base; if (nn > NPB) nn = NPB;

    {   // stage x tile (float4)
        const float4* xg = (const float4*)(x + (size_t)base * FIN);
        float4* xs4 = (float4*)xs;
        int tot4 = nn * FIN / 4;
        for (int i = t; i < tot4; i += 256) xs4[i] = xg[i];
        for (int i = tot4 * 4 + t; i < NPB * FIN; i += 256) xs[i] = 0.f;
    }
    __syncthreads();

    int grp = t >> 6;       // 0..3, each grp = one wave, 8 nodes
    int l = t & 63;
    int col0 = l * 2;

    float2 acc[8];
#pragma unroll
    for (int j = 0; j < 8; j++) { acc[j].x = 0.f; acc[j].y = 0.f; }

    for (int k4 = 0; k4 < FIN; k4 += 4) {
        float4 xv[8];
#pragma unroll
        for (int j = 0; j < 8; j++)
            xv[j] = *(const float4*)&xs[(grp * 8 + j) * FIN + k4];
#pragma unroll
        for (int kk = 0; kk < 4; kk++) {
            float2 wv = *(const float2*)&W[(size_t)(k4 + kk) * F_HID + col0];
#pragma unroll
            for (int j = 0; j < 8; j++) {
                float xk = (&xv[j].x)[kk];
                acc[j].x += xk * wv.x;
                acc[j].y += xk * wv.y;
            }
        }
    }

    float ws0 = a_s[col0], ws1 = a_s[col0 + 1];
    float wd0 = a_d[col0], wd1 = a_d[col0 + 1];
#pragma unroll
    for (int j = 0; j < 8; j++) {
        int node = base + grp * 8 + j;
        bool ok = node < n;
        if (ok)
            hb[((size_t)node << 6) + l] = bf16_rne(acc[j].x) | (bf16_rne(acc[j].y) << 16);
        float vs = acc[j].x * ws0 + acc[j].y * ws1;
        float vd = acc[j].x * wd0 + acc[j].y * wd1;
#pragma unroll
        for (int off = 8; off >= 1; off >>= 1) {
            vs += __shfl_xor(vs, off);
            vd += __shfl_xor(vd, off);
        }
        if (ok && (l & 15) == 0) {
            int hd = l >> 4;
            asrc[node * HEADS + hd] = vs;
            adst[node * HEADS + hd] = vd;
        }
    }
}

// Wave-per-node single-pass online-softmax aggregate over bf16x2 h.
// Edge phase (alphas): lane = hd(l>>4) x edge-slot ci(l&15).
// Gather phase: lane = edge 4q+(l>>4), head (l&15)>>2, u32-quad l&3;
//   each 16-lane group loads one full 256B row via dwordx4 (coalesced).
__global__ __launch_bounds__(256) void aggregate(const uint32_t* __restrict__ hb,
                                                 const float* __restrict__ asrc,
                                                 const float* __restrict__ adst,
                                                 const int* __restrict__ row_start,
                                                 const int* __restrict__ deg,
                                                 const int* __restrict__ csr_src,
                                                 const float* __restrict__ bias,
                                                 float* __restrict__ xout, int n) {
    int d = blockIdx.x * 4 + (threadIdx.x >> 6);
    if (d >= n) return;
    int l = threadIdx.x & 63;
    int hd = l >> 4;                 // edge-phase head
    int ci = l & 15;                 // edge-phase edge slot
    int hh = (l & 15) >> 2;          // gather-phase head
    int kk = l & 3;                  // gather-phase u32 quad
    int permb = (hh * 16 + (l >> 4)) * 4;   // bpermute byte addr (+16q per quad)
    int rowoff = hh * 64 + kk * 16;         // byte offset within 256B row

    int start = row_start[d];
    int cnt = deg[d];
    float ad = adst[d * HEADS + hd];
    float e_self = lrelu(asrc[d * HEADS + hd] + ad);

    float m = e_self;
    float dsum = 0.f;
    v2f a0 = {0.f, 0.f}, a1 = {0.f, 0.f}, a2 = {0.f, 0.f}, a3 = {0.f, 0.f};
    const char* hbbase = (const char*)hb;

    for (int j0 = 0; j0 < cnt; j0 += 16) {
        int ncnt = cnt - j0; if (ncnt > 16) ncnt = 16;
        bool valid = ci < ncnt;
        int s = 0;
        float e = -1e30f;
        if (valid) {
            s = csr_src[start + j0 + ci];
            e = lrelu(asrc[s * HEADS + hd] + ad);
        }
        float cmax = e;
        cmax = fmaxf(cmax, __shfl_xor(cmax, 8));
        cmax = fmaxf(cmax, __shfl_xor(cmax, 4));
        cmax = fmaxf(cmax, __shfl_xor(cmax, 2));
        cmax = fmaxf(cmax, __shfl_xor(cmax, 1));
        float mnew = fmaxf(m, cmax);
        float fac = __expf(m - mnew);      // ==1 when max unchanged
        m = mnew;
        dsum *= fac;
        float pe = valid ? __expf(e - m) : 0.f;
        dsum += pe;
        // rescale gather accumulators (fac permuted to gather-layout head)
        float facg = bperm_f(permb, fac);
        v2f f2 = {facg, facg};
        a0 *= f2; a1 *= f2; a2 *= f2; a3 *= f2;

        int nq = (ncnt + 3) >> 2;
        for (int q = 0; q < nq; ++q) {
            int pb = permb + 16 * q;
            float pj = bperm_f(pb, pe);
            int sj = __builtin_amdgcn_ds_bpermute(pb, s);
            uint4 u = *(const uint4*)(hbbase + (((uint32_t)sj) << 8) + rowoff);
            v2f p2 = {pj, pj};
            a0 += p2 * up2(u.x);
            a1 += p2 * up2(u.y);
            a2 += p2 * up2(u.z);
            a3 += p2 * up2(u.w);
        }
    }

    // denominator (edge layout, uniform per head group)
    dsum += __shfl_xor(dsum, 8);
    dsum += __shfl_xor(dsum, 4);
    dsum += __shfl_xor(dsum, 2);
    dsum += __shfl_xor(dsum, 1);
    float ps = __expf(e_self - m);
    float inv = 1.f / (dsum + ps + 1e-16f);
    // permute to gather layout
    float psg = bperm_f(permb, ps);
    float invg = bperm_f(permb, inv);

    // reduce across the 4 edge-subgroups (lanes ^16, ^32)
    a0 += vshflxor(a0, 16); a0 += vshflxor(a0, 32);
    a1 += vshflxor(a1, 16); a1 += vshflxor(a1, 32);
    a2 += vshflxor(a2, 16); a2 += vshflxor(a2, 32);
    a3 += vshflxor(a3, 16); a3 += vshflxor(a3, 32);

    // self-loop contribution + normalize
    uint4 us = *(const uint4*)(hbbase + (((uint32_t)d) << 8) + rowoff);
    v2f ps2 = {psg, psg};
    a0 += ps2 * up2(us.x);
    a1 += ps2 * up2(us.y);
    a2 += ps2 * up2(us.z);
    a3 += ps2 * up2(us.w);
    v2f iv2 = {invg, invg};
    a0 *= iv2; a1 *= iv2; a2 *= iv2; a3 *= iv2;

    // head mean (lanes ^4, ^8 differ in head)
    a0 += vshflxor(a0, 4); a0 += vshflxor(a0, 8);
    a1 += vshflxor(a1, 4); a1 += vshflxor(a1, 8);
    a2 += vshflxor(a2, 4); a2 += vshflxor(a2, 8);
    a3 += vshflxor(a3, 4); a3 += vshflxor(a3, 8);

    if (l < 4) {   // lane kk=l writes channels 8l..8l+7
        const float4* bv = (const float4*)&bias[l * 8];
        float4 b0 = bv[0], b1 = bv[1];
        float4 o0, o1;
        o0.x = 0.25f * a0.x + b0.x; o0.y = 0.25f * a0.y + b0.y;
        o0.z = 0.25f * a1.x + b0.z; o0.w = 0.25f * a1.y + b0.w;
        o1.x = 0.25f * a2.x + b1.x; o1.y = 0.25f * a2.y + b1.y;
        o1.z = 0.25f * a3.x + b1.z; o1.w = 0.25f * a3.y + b1.w;
        o0.x = o0.x > 0.f ? o0.x : 0.f;  o0.y = o0.y > 0.f ? o0.y : 0.f;
        o0.z = o0.z > 0.f ? o0.z : 0.f;  o0.w = o0.w > 0.f ? o0.w : 0.f;
        o1.x = o1.x > 0.f ? o1.x : 0.f;  o1.y = o1.y > 0.f ? o1.y : 0.f;
        o1.z = o1.z > 0.f ? o1.z : 0.f;  o1.w = o1.w > 0.f ? o1.w : 0.f;
        float4* op = (float4*)&xout[(size_t)d * HID + l * 8];
        op[0] = o0;
        op[1] = o1;
    }
}

// ---------------- pooling + MLP ----------------

__global__ void pool_sum(const float* __restrict__ x, int n, float* __restrict__ g) {
    __shared__ float sm[256];
    int t = threadIdx.x;
    int c = t & 31;
    int r = t >> 5;   // 8 node-rows per block
    float acc = 0.f;
    for (int i = blockIdx.x * 8 + r; i < n; i += gridDim.x * 8)
        acc += x[(size_t)i * HID + c];
    sm[t] = acc;
    __syncthreads();
    if (t < 32) {
        float v = 0.f;
#pragma unroll
        for (int k = 0; k < 8; k++) v += sm[t + 32 * k];
        atomicAdd(&g[t], v);
    }
}

__global__ void mlp_final(const float* __restrict__ g,
                          const float* __restrict__ lw1, const float* __restrict__ lb1,
                          const float* __restrict__ lw2, const float* __restrict__ lb2,
                          float* __restrict__ out, float invn) {
    __shared__ float gm[32];
    int t = threadIdx.x;
    if (t < 32) gm[t] = g[t] * invn;
    __syncthreads();
    float q = 0.f;
    if (t < 16) {
        q = lb1[t];
        for (int c = 0; c < 32; c++) q += gm[c] * lw1[c * 16 + t];
        q = q > 0.f ? q : 0.f;
        q *= lw2[t];
    }
#pragma unroll
    for (int off = 8; off >= 1; off >>= 1) q += __shfl_xor(q, off);
    if (t == 0) out[0] = q + lb2[0];
}

// ---------------- launch ----------------

extern "C" void kernel_launch(void* const* d_in, const int* in_sizes, int n_in,
                              void* d_out, int out_size, void* d_ws, size_t ws_size,
                              hipStream_t stream) {
    const float* x   = (const float*)d_in[0];
    const int*   ei  = (const int*)d_in[1];
    const float* W1  = (const float*)d_in[2];
    const float* as1 = (const float*)d_in[3];
    const float* ad1 = (const float*)d_in[4];
    const float* b1  = (const float*)d_in[5];
    const float* W2  = (const float*)d_in[6];
    const float* as2 = (const float*)d_in[7];
    const float* ad2 = (const float*)d_in[8];
    const float* b2  = (const float*)d_in[9];
    const float* W3  = (const float*)d_in[10];
    const float* as3 = (const float*)d_in[11];
    const float* ad3 = (const float*)d_in[12];
    const float* b3  = (const float*)d_in[13];
    const float* lw1 = (const float*)d_in[14];
    const float* lb1 = (const float*)d_in[15];
    const float* lw2 = (const float*)d_in[16];
    const float* lb2 = (const float*)d_in[17];
    float* out = (float*)d_out;

    int n = in_sizes[0] / 128;   // 100000
    int E = in_sizes[1] / 2;     // 1600000
    int B = (n + 255) / 256;
    int nb = (n + 31) >> BSHIFT; // 3125 buckets

    // workspace carve (256B aligned)
    char* p = (char*)d_ws;
    auto alloc = [&](size_t bytes) -> void* {
        void* r = (void*)p;
        p += (bytes + 255) & ~(size_t)255;
        return r;
    };
    int* deg       = (int*)alloc((size_t)n * 4);
    int* row_start = (int*)alloc((size_t)n * 4);
    int* gcursor   = (int*)alloc((size_t)nb * 4);
    int* partial   = (int*)alloc((size_t)B * 4);
    int* csr       = (int*)alloc((size_t)E * 4);
    uint32_t* tmp  = (uint32_t*)alloc((size_t)E * 4);
    float* asrc    = (float*)alloc((size_t)n * HEADS * 4);
    float* adst    = (float*)alloc((size_t)n * HEADS * 4);
    uint32_t* hb   = (uint32_t*)alloc((size_t)n * 64 * 4);   // bf16x2 packed h
    float* xA      = (float*)alloc((size_t)n * HID * 4);
    float* xB      = (float*)alloc((size_t)n * HID * 4);
    float* g       = (float*)alloc(32 * 4);

    // CSR build (shared across all 3 layers)
    hipMemsetAsync(deg, 0, (size_t)n * 4, stream);
    deg_hist<<<(E + 255) / 256, 256, 0, stream>>>(ei, E, deg);
    scan_partial<<<B, 256, 0, stream>>>(deg, n, partial);
    scan_exclusive<<<1, 512, 0, stream>>>(partial, B);
    scan_final<<<B, 256, 0, stream>>>(deg, n, partial, row_start);
    init_gcursor<<<(nb + 255) / 256, 256, 0, stream>>>(row_start, n, nb, gcursor);
    bucket_scatter<<<64, 512, 0, stream>>>(ei, E, nb, gcursor, tmp);
    bucket_sort<<<nb, 256, 0, stream>>>(tmp, row_start, n, E, csr);

    int gb = (n + 31) / 32;
    int ggb = (n + 3) / 4;

    // layer 1
    gemm_h<128><<<gb, 256, 0, stream>>>(x, W1, as1, ad1, hb, asrc, adst, n);
    aggregate<<<ggb, 256, 0, stream>>>(hb, asrc, adst, row_start, deg, csr, b1, xA, n);

    // layer 2
    gemm_h<32><<<gb, 256, 0, stream>>>(xA, W2, as2, ad2, hb, asrc, adst, n);
    aggregate<<<ggb, 256, 0, stream>>>(hb, asrc, adst, row_start, deg, csr, b2, xB, n);

    // layer 3
    gemm_h<32><<<gb, 256, 0, stream>>>(xB, W3, as3, ad3, hb, asrc, adst, n);
    aggregate<<<ggb, 256, 0, stream>>>(hb, asrc, adst, row_start, deg, csr, b3, xA, n);

    // pooling + MLP
    hipMemsetAsync(g, 0, 32 * 4, stream);
    pool_sum<<<256, 256, 0, stream>>>(xA, n, g);
    mlp_final<<<1, 64, 0, stream>>>(g, lw1, lb1, lw2, lb2, out, 1.0f / (float)n);
}